// Round 2
// baseline (2896.237 us; speedup 1.0000x reference)
//
#include <hip/hip_runtime.h>
#include <hip/hip_bf16.h>

#define D1 4096
#define V2n 2048
#define NNZ1c 32768
#define NNZ2c 16384

// ---------------- CSR build ----------------
__global__ void k_hist(const int* __restrict__ rows, int nnz, int* __restrict__ cnt) {
    int e = blockIdx.x * 256 + threadIdx.x;
    if (e < nnz) atomicAdd(&cnt[rows[e]], 1);
}

// one block, 256 threads; V divisible by 256. cnt becomes cursor (exclusive prefix).
__global__ void k_scan(int* __restrict__ cnt, int* __restrict__ rs, int V, int nnz) {
    __shared__ int sums[256];
    int t = threadIdx.x;
    int chunk = V / 256;
    int base = t * chunk;
    int s = 0;
    for (int i = 0; i < chunk; ++i) s += cnt[base + i];
    sums[t] = s;
    __syncthreads();
    if (t == 0) {
        int run = 0;
        for (int i = 0; i < 256; ++i) { int c = sums[i]; sums[i] = run; run += c; }
    }
    __syncthreads();
    int p = sums[t];
    for (int i = 0; i < chunk; ++i) {
        int c = cnt[base + i];
        rs[base + i] = p;
        cnt[base + i] = p;   // cursor for scatter
        p += c;
    }
    if (t == 0) rs[V] = nnz;
}

__global__ void k_scatter(const int* __restrict__ rows, const int* __restrict__ cols,
                          const float* __restrict__ vals, int nnz, int* __restrict__ cur,
                          int* __restrict__ ccol, float* __restrict__ cval) {
    int e = blockIdx.x * 256 + threadIdx.x;
    if (e < nnz) {
        int p = atomicAdd(&cur[rows[e]], 1);
        ccol[p] = cols[e];
        cval[p] = vals[e];
    }
}

// ---------------- layer 1 ----------------
// z0[v*64+b] = x[b*4096+v]
__global__ void k_transpose(const float* __restrict__ x, float* __restrict__ z0) {
    int tid = blockIdx.x * 256 + threadIdx.x;   // 262144
    int b = tid & 63, v = tid >> 6;
    z0[v * 64 + b] = x[b * D1 + v];
}

// one Chebyshev step on [V1, 64]: zo = first ? (Az1 - z1) : 2*(Az1 - z1) - z0
__global__ void k_cheb1(const int* __restrict__ rs, const int* __restrict__ ccol,
                        const float* __restrict__ cval,
                        const float* __restrict__ z1, const float* __restrict__ z0,
                        float* __restrict__ zo, int first) {
    int tid = blockIdx.x * 256 + threadIdx.x;   // 262144
    int b = tid & 63, v = tid >> 6;
    int e0 = rs[v], e1 = rs[v + 1];
    float s = 0.f;
    for (int e = e0; e < e1; ++e) s = fmaf(cval[e], z1[ccol[e] * 64 + b], s);
    float t1 = s - z1[tid];
    zo[tid] = first ? t1 : 2.f * t1 - z0[tid];
}

// y1h[u][fin*64+b] = maxpool over v in {2u,2u+1} of relu(sum_k T1[k][v][b]*W1[fin][k] + b1[fin])
__global__ void k_gemm1(const float* __restrict__ T1, const float* __restrict__ W1,
                        const float* __restrict__ b1, float* __restrict__ y1h) {
    __shared__ float sT[25 * 128];
    __shared__ float sW[32 * 25];
    __shared__ float sB[32];
    int u = blockIdx.x;           // 0..2047
    int t = threadIdx.x;
    for (int idx = t; idx < 3200; idx += 256) {
        int k = idx >> 7, r = idx & 127;       // r = d*64+b, d in {0,1}
        sT[idx] = T1[k * (D1 * 64) + (2 * u) * 64 + r];
    }
    for (int idx = t; idx < 800; idx += 256) sW[idx] = W1[idx];
    if (t < 32) sB[t] = b1[t];
    __syncthreads();
    int b = t & 63, fin0 = (t >> 6) * 8;
    float a0[8], a1[8];
#pragma unroll
    for (int j = 0; j < 8; ++j) { a0[j] = 0.f; a1[j] = 0.f; }
    for (int k = 0; k < 25; ++k) {
        float x0 = sT[k * 128 + b], x1 = sT[k * 128 + 64 + b];
#pragma unroll
        for (int j = 0; j < 8; ++j) {
            float w = sW[(fin0 + j) * 25 + k];
            a0[j] = fmaf(x0, w, a0[j]);
            a1[j] = fmaf(x1, w, a1[j]);
        }
    }
#pragma unroll
    for (int j = 0; j < 8; ++j) {
        float bias = sB[fin0 + j];
        float r0 = fmaxf(a0[j] + bias, 0.f);
        float r1 = fmaxf(a1[j] + bias, 0.f);
        y1h[u * 2048 + (fin0 + j) * 64 + b] = fmaxf(r0, r1);
    }
}

// ---------------- layer 2: fused cheb step + dense contribution ----------------
// mode 0: k==0 (zS = z1 slice, y2 = bias + contrib, no recurrence/write)
// mode 1: k==1 (first Ls)    mode 2: general
// NOTE: zo may alias z0 (own-row element-wise read happens before write, in-thread).
__global__ void k_conv2(const int* __restrict__ rs, const int* __restrict__ ccol,
                        const float* __restrict__ cval,
                        const float* __restrict__ z1, const float* __restrict__ z0,
                        float* __restrict__ zo, const float* __restrict__ W2,
                        const float* __restrict__ b2,
                        float* __restrict__ y2, int k, int mode) {
    __shared__ float zS[2048];        // [fin*64 + b]
    __shared__ float wS[64 * 33];     // [f][fin], padded stride 33
    int v = blockIdx.x, t = threadIdx.x;
    if (mode == 0) {
        for (int c = t; c < 2048; c += 256) zS[c] = z1[v * 2048 + c];
    } else {
        int e0 = rs[v], e1 = rs[v + 1];
        for (int c = t; c < 2048; c += 256) {
            float s = 0.f;
            for (int e = e0; e < e1; ++e) s = fmaf(cval[e], z1[ccol[e] * 2048 + c], s);
            float t1 = s - z1[v * 2048 + c];
            float zn = (mode == 1) ? t1 : 2.f * t1 - z0[v * 2048 + c];
            zo[v * 2048 + c] = zn;
            zS[c] = zn;
        }
    }
    for (int idx = t; idx < 2048; idx += 256) {
        int f = idx >> 5, fin = idx & 31;
        wS[f * 33 + fin] = W2[f * 800 + fin * 25 + k];
    }
    __syncthreads();
    int tf = t & 15, tb = t >> 4;
    int f0 = tf * 4, b0 = tb * 4;
    float acc[4][4];
#pragma unroll
    for (int i = 0; i < 4; ++i)
#pragma unroll
        for (int j = 0; j < 4; ++j) acc[i][j] = 0.f;
    for (int fin = 0; fin < 32; ++fin) {
        float zv[4], wv[4];
#pragma unroll
        for (int bb = 0; bb < 4; ++bb) zv[bb] = zS[fin * 64 + b0 + bb];
#pragma unroll
        for (int ff = 0; ff < 4; ++ff) wv[ff] = wS[(f0 + ff) * 33 + fin];
#pragma unroll
        for (int bb = 0; bb < 4; ++bb)
#pragma unroll
            for (int ff = 0; ff < 4; ++ff) acc[bb][ff] = fmaf(zv[bb], wv[ff], acc[bb][ff]);
    }
    // y2 layout [v][b][f]
#pragma unroll
    for (int bb = 0; bb < 4; ++bb) {
        float* p = &y2[v * 4096 + (b0 + bb) * 64 + f0];
        float4 old;
        if (mode == 0) {
            old.x = b2[f0]; old.y = b2[f0 + 1];
            old.z = b2[f0 + 2]; old.w = b2[f0 + 3];
        } else {
            old = *(const float4*)p;
        }
        float4 nv = make_float4(old.x + acc[bb][0], old.y + acc[bb][1],
                                old.z + acc[bb][2], old.w + acc[bb][3]);
        *(float4*)p = nv;
    }
}

// relu + maxpool(p=2) + transpose: h2T[(u*64+f)*64 + b] = max over v in {2u,2u+1} relu(y2[v][b][f])
__global__ void k_pool2(const float* __restrict__ y2, float* __restrict__ h2T) {
    __shared__ float mS[64 * 65];
    int u = blockIdx.x, t = threadIdx.x;
    for (int idx = t; idx < 4096; idx += 256) {
        int b = idx >> 6, f = idx & 63;
        float a = y2[(2 * u) * 4096 + idx];
        float c = y2[(2 * u + 1) * 4096 + idx];
        mS[f * 65 + b] = fmaxf(fmaxf(a, 0.f), fmaxf(c, 0.f));
    }
    __syncthreads();
    for (int idx = t; idx < 4096; idx += 256) {
        int f = idx >> 6, b = idx & 63;
        h2T[(u * 64 + f) * 64 + b] = mS[f * 65 + b];
    }
}

// ---------------- FC ----------------
// split-K GEMM: fc1o[j*64+b] += sum_k fc1_W[j][k] * h2T[k*64+b]; grid = 8 j-tiles x 64 k-splits
__global__ void k_fc1(const float* __restrict__ h2T, const float* __restrict__ fW,
                      float* __restrict__ fc1o) {
    __shared__ float wT[64 * 65];
    __shared__ float hT[64 * 64];
    int bx = blockIdx.x;
    int jt = bx & 7, ks = bx >> 3;
    int j0g = jt * 64, k0g = ks * 1024;
    int t = threadIdx.x;
    int tb = t & 15, tj = t >> 4;
    float acc[4][4];
#pragma unroll
    for (int i = 0; i < 4; ++i)
#pragma unroll
        for (int j = 0; j < 4; ++j) acc[i][j] = 0.f;
    for (int kc = 0; kc < 16; ++kc) {
        int kbase = k0g + kc * 64;
        __syncthreads();
        for (int idx = t; idx < 4096; idx += 256) {
            int jl = idx >> 6, kl = idx & 63;
            wT[jl * 65 + kl] = fW[(size_t)(j0g + jl) * 65536 + kbase + kl];
        }
        for (int idx = t; idx < 4096; idx += 256) {
            hT[idx] = h2T[(size_t)kbase * 64 + idx];
        }
        __syncthreads();
        for (int kl = 0; kl < 64; ++kl) {
            float hv[4], wv[4];
#pragma unroll
            for (int bb = 0; bb < 4; ++bb) hv[bb] = hT[kl * 64 + tb * 4 + bb];
#pragma unroll
            for (int jj = 0; jj < 4; ++jj) wv[jj] = wT[(tj * 4 + jj) * 65 + kl];
#pragma unroll
            for (int bb = 0; bb < 4; ++bb)
#pragma unroll
                for (int jj = 0; jj < 4; ++jj) acc[bb][jj] = fmaf(hv[bb], wv[jj], acc[bb][jj]);
        }
    }
#pragma unroll
    for (int bb = 0; bb < 4; ++bb)
#pragma unroll
        for (int jj = 0; jj < 4; ++jj)
            atomicAdd(&fc1o[(j0g + tj * 4 + jj) * 64 + tb * 4 + bb], acc[bb][jj]);
}

// out[b*10+c] = sum_j relu(fc1o[j][b] + fc1_b[j]) * fc2_W[c][j] + fc2_b[c]
__global__ void k_fc2(const float* __restrict__ fc1o, const float* __restrict__ fb1,
                      const float* __restrict__ fW2, const float* __restrict__ fb2,
                      float* __restrict__ out) {
    int tid = blockIdx.x * 64 + threadIdx.x;   // grid 10 x 64
    if (tid >= 640) return;
    int b = tid / 10, c = tid % 10;
    float s = fb2[c];
    for (int j = 0; j < 512; ++j) {
        float a = fmaxf(fc1o[j * 64 + b] + fb1[j], 0.f);
        s = fmaf(a, fW2[c * 512 + j], s);
    }
    out[b * 10 + c] = s;
}

extern "C" void kernel_launch(void* const* d_in, const int* in_sizes, int n_in,
                              void* d_out, int out_size, void* d_ws, size_t ws_size,
                              hipStream_t stream) {
    const float* x   = (const float*)d_in[0];
    const int* L1r   = (const int*)d_in[1];
    const int* L1c   = (const int*)d_in[2];
    const float* L1v = (const float*)d_in[3];
    const int* L2r   = (const int*)d_in[4];
    const int* L2c   = (const int*)d_in[5];
    const float* L2v = (const float*)d_in[6];
    const float* cl1W = (const float*)d_in[7];
    const float* cl1b = (const float*)d_in[8];
    const float* cl2W = (const float*)d_in[9];
    const float* cl2b = (const float*)d_in[10];
    const float* fc1W = (const float*)d_in[11];
    const float* fc1b = (const float*)d_in[12];
    const float* fc2W = (const float*)d_in[13];
    const float* fc2b = (const float*)d_in[14];
    float* out = (float*)d_out;

    // ---- arena (floats), small stuff first, big buffers overlaid ----
    float* Wf = (float*)d_ws;
    size_t off = 0;
    auto alloc = [&](size_t n) { float* p = Wf + off; off += n; return p; };
    int* cnt1  = (int*)alloc(4096);
    int* rs1   = (int*)alloc(4097);
    int* ccol1 = (int*)alloc(NNZ1c);
    int* cnt2  = (int*)alloc(2048);
    int* rs2   = (int*)alloc(2049);
    int* ccol2 = (int*)alloc(16384 + 2);   // pad to even
    float* cval1 = alloc(NNZ1c);
    float* cval2 = alloc(NNZ2c);
    float* fc1o  = alloc(512 * 64);
    float* y2    = alloc(2048ull * 4096);  // 33.5MB; T1 (26.2MB) overlays this region
    float* y1h   = alloc(2048ull * 2048);  // 16.8MB; layer-2 z ping
    float* zA    = alloc(2048ull * 2048);  // 16.8MB; layer-2 z pong; h2T overlays
    float* T1  = y2;                       // layer-1 only (dead before y2 is written)
    float* h2T = zA;                       // post-pool activations (z buffers dead)
    // total ≈ 67.7 MB

    hipMemsetAsync(cnt1, 0, 4096 * sizeof(int), stream);
    hipMemsetAsync(cnt2, 0, 2048 * sizeof(int), stream);
    hipMemsetAsync(fc1o, 0, 512 * 64 * sizeof(float), stream);

    // CSR build
    k_hist<<<NNZ1c / 256, 256, 0, stream>>>(L1r, NNZ1c, cnt1);
    k_hist<<<NNZ2c / 256, 256, 0, stream>>>(L2r, NNZ2c, cnt2);
    k_scan<<<1, 256, 0, stream>>>(cnt1, rs1, D1, NNZ1c);
    k_scan<<<1, 256, 0, stream>>>(cnt2, rs2, V2n, NNZ2c);
    k_scatter<<<NNZ1c / 256, 256, 0, stream>>>(L1r, L1c, L1v, NNZ1c, cnt1, ccol1, cval1);
    k_scatter<<<NNZ2c / 256, 256, 0, stream>>>(L2r, L2c, L2v, NNZ2c, cnt2, ccol2, cval2);

    // layer 1: Chebyshev recurrence on [4096, 64]; all 25 slices stored in T1
    const int S1 = D1 * 64;
    k_transpose<<<1024, 256, 0, stream>>>(x, T1);
    for (int k = 1; k < 25; ++k) {
        k_cheb1<<<1024, 256, 0, stream>>>(rs1, ccol1, cval1,
                                          T1 + (size_t)(k - 1) * S1,
                                          T1 + (size_t)(k >= 2 ? k - 2 : 0) * S1,
                                          T1 + (size_t)k * S1, k == 1 ? 1 : 0);
    }
    k_gemm1<<<2048, 256, 0, stream>>>(T1, cl1W, cl1b, y1h);   // writes y1h; T1 dead after

    // layer 2: fused recurrence + contribution; ping-pong {y1h, zA}, zo aliases z0
    float* zbuf[2] = {y1h, zA};
    for (int k = 0; k < 25; ++k) {
        int mode = (k == 0) ? 0 : (k == 1 ? 1 : 2);
        const float* z1p = (k == 0) ? y1h : zbuf[(k - 1) & 1];
        float* zop = zbuf[k & 1];
        const float* z0p = zop;   // T_{k-2} lives where T_k is written (safe: own-row RAW in-thread)
        k_conv2<<<2048, 256, 0, stream>>>(rs2, ccol2, cval2, z1p, z0p, zop,
                                          cl2W, cl2b, y2, k, mode);
    }
    k_pool2<<<1024, 256, 0, stream>>>(y2, h2T);   // z buffers dead; h2T overlays zA

    // FC
    k_fc1<<<512, 256, 0, stream>>>(h2T, fc1W, fc1o);
    k_fc2<<<10, 64, 0, stream>>>(fc1o, fc1b, fc2W, fc2b, out);
}